// Round 20
// baseline (125.707 us; speedup 1.0000x reference)
//
#include <hip/hip_runtime.h>

static constexpr int NN = 50000;    // nodes
static constexpr int NE = 1600000;  // edges
static constexpr int CH = 128;
static constexpr int NCLS = 40;

static constexpr int NPB  = 64;                        // nodes per gather bucket
static constexpr int NBUK = (NN + NPB - 1) / NPB;      // 782 gather blocks
static constexpr int NPB_SC = 256;                     // nodes per scatter bucket
static constexpr int NBUK_SC = (NN + NPB_SC - 1) / NPB_SC;  // 196
static constexpr int EPB  = 8192;                      // edges per hist/scatter block
static constexpr int NHB  = (NE + EPB - 1) / EPB;      // 196
static constexpr int NS   = NBUK_SC * NHB;             // 38416 hist entries
static constexpr int SCAN_B = 256;
static constexpr int SCAN_SHIFT = 8;                   // log2(SCAN_B)
static constexpr int NSB  = (NS + SCAN_B - 1) / SCAN_B; // 151 (<=256)
static constexpr int NROWP = ((NN + 63) / 64) * 64;    // 50048 padded rows
static constexpr int PAD = 136;                        // W1^T padded row
static constexpr int GEMM_BLKS = (NN + 63) / 64;       // 782
static constexpr int CAP = 3072;                       // max edges per 64-node bucket
static constexpr size_t VSTRIDE = (size_t)NROWP * NCLS; // elements per replica
static constexpr int NCOPY = 8;                        // one replica per XCD

typedef __attribute__((ext_vector_type(8))) short bf16x8;
typedef __attribute__((ext_vector_type(4))) float f32x4;

// ---- bf16 helpers (bit-level, RNE) ----
__device__ __forceinline__ float bflo(unsigned v) {
    return __uint_as_float((v & 0xFFFFu) << 16);
}
__device__ __forceinline__ float bfhi(unsigned v) {
    return __uint_as_float(v & 0xFFFF0000u);
}
__device__ __forceinline__ unsigned short f2bf(float f) {
    unsigned u = __float_as_uint(f);
    u += 0x7FFFu + ((u >> 16) & 1u);   // round to nearest even
    return (unsigned short)(u >> 16);
}
// actual XCD id of this wave (gfx950, HW-verified m09); wave-uniform
__device__ __forceinline__ int xcc_id() {
    int x;
    asm volatile("s_getreg_b32 %0, hwreg(HW_REG_XCC_ID)" : "=s"(x));
    return x & 7;
}

// ---------------------------------------------------------------------------
// fused_pre: blocks [0,NHB): edge histogram (src>>8, 196 coarse buckets) -> H
//            blocks [NHB,NHB+64): W1^T bf16 padded transpose -> Wt_g
//            blocks [NHB+64,NHB+88): Mt=(W2@Wfc)^T bf16 + cfc=b2@Wfc
// ---------------------------------------------------------------------------
__global__ __launch_bounds__(256)
void fused_pre(const int* __restrict__ src, int* __restrict__ H,
               const float* __restrict__ W1, unsigned short* __restrict__ Wt_g,
               const float* __restrict__ W2, const float* __restrict__ Wfc,
               const float* __restrict__ b2, unsigned short* __restrict__ Mt,
               float* __restrict__ cfc)
{
    __shared__ int h[NBUK_SC];
    const int t = threadIdx.x;
    const int b = blockIdx.x;

    if (b < NHB) {
        for (int i = t; i < NBUK_SC; i += 256) h[i] = 0;
        __syncthreads();
        const int base4 = b * (EPB / 4);
        const int4* src4 = reinterpret_cast<const int4*>(src);
        for (int i = t; i < EPB / 4; i += 256) {
            const int idx = base4 + i;
            if (idx < NE / 4) {
                const int4 v = src4[idx];
                atomicAdd(&h[v.x >> 8], 1);
                atomicAdd(&h[v.y >> 8], 1);
                atomicAdd(&h[v.z >> 8], 1);
                atomicAdd(&h[v.w >> 8], 1);
            }
        }
        __syncthreads();
        for (int i = t; i < NBUK_SC; i += 256) H[i * NHB + b] = h[i];
    } else if (b < NHB + 64) {
        const int idx = (b - NHB) * 256 + t;   // 0..16383
        const int c = idx >> 7;
        const int k = idx & 127;
        Wt_g[c * PAD + k] = f2bf(W1[k * 128 + c]);
    } else {
        const int idx = (b - NHB - 64) * 256 + t;   // 0..6143
        if (idx < 48 * 128) {
            const int c = idx >> 7;
            const int k = idx & 127;
            float a = 0.f;
            if (c < NCLS) {
                #pragma unroll 16
                for (int j = 0; j < 128; ++j) a += W2[k * 128 + j] * Wfc[j * NCLS + c];
            }
            Mt[c * 128 + k] = f2bf(a);
        }
        if (b == NHB + 64 && t < NCLS) {
            float a = 0.f;
            #pragma unroll 16
            for (int j = 0; j < 128; ++j) a += b2[j] * Wfc[j * NCLS + t];
            cfc[t] = a;
        }
    }
}

__global__ __launch_bounds__(SCAN_B)
void scan_local(int* __restrict__ H, int* __restrict__ bsum)
{
    __shared__ int buf[SCAN_B];
    const int t = threadIdx.x;
    const int g = blockIdx.x * SCAN_B + t;
    const int v = (g < NS) ? H[g] : 0;
    buf[t] = v;
    __syncthreads();
    #pragma unroll
    for (int off = 1; off < SCAN_B; off <<= 1) {
        const int x = (t >= off) ? buf[t - off] : 0;
        __syncthreads();
        buf[t] += x;
        __syncthreads();
    }
    if (g < NS) H[g] = buf[t] - v;     // exclusive within scan-block
    if (t == SCAN_B - 1) bsum[blockIdx.x] = buf[t];
}

__global__ __launch_bounds__(SCAN_B)
void scan_bsums(int* __restrict__ bsum)
{
    __shared__ int buf[SCAN_B];
    const int t = threadIdx.x;
    const int v = (t < NSB) ? bsum[t] : 0;
    buf[t] = v;
    __syncthreads();
    #pragma unroll
    for (int off = 1; off < SCAN_B; off <<= 1) {
        const int x = (t >= off) ? buf[t - off] : 0;
        __syncthreads();
        buf[t] += x;
        __syncthreads();
    }
    if (t < NSB) bsum[t] = buf[t] - v;  // exclusive base per scan-block
    if (t == SCAN_B - 1) bsum[NSB] = buf[t];
}

// ---------------------------------------------------------------------------
// fused_mid: blocks [0,NHB): coarse bucket_scatter (196 buckets, ~42-edge
// runs); blocks [NHB,+782): gemm1v writing all 8 V1 replicas.
// ---------------------------------------------------------------------------
__global__ __launch_bounds__(256)
void fused_mid(const int* __restrict__ src, const int* __restrict__ dst,
               const int* __restrict__ H, const int* __restrict__ bsum,
               int* __restrict__ EP,
               const float* __restrict__ X, const unsigned short* __restrict__ Wt_g,
               const float* __restrict__ b, const unsigned short* __restrict__ Mt,
               unsigned short* __restrict__ V1R)
{
    __shared__ __align__(16) unsigned short Wt[128 * PAD];   // 34.8 KB
    __shared__ __align__(16) unsigned short Fa[64 * PAD];    // 17.4 KB
    __shared__ __align__(16) unsigned short Va[64 * NCLS];   // 5 KB
    __shared__ float bl[128];
    __shared__ int cur[NBUK_SC];

    const int t = threadIdx.x;

    if (blockIdx.x < NHB) {
        // ---------------- coarse bucket_scatter ----------------
        const int bb = blockIdx.x;
        for (int i = t; i < NBUK_SC; i += 256) {
            const int x = i * NHB + bb;
            cur[i] = H[x] + bsum[x >> SCAN_SHIFT];
        }
        __syncthreads();
        const int base4 = bb * (EPB / 4);
        const int4* src4 = reinterpret_cast<const int4*>(src);
        const int4* dst4 = reinterpret_cast<const int4*>(dst);
        for (int i = t; i < EPB / 4; i += 256) {
            const int idx = base4 + i;
            if (idx < NE / 4) {
                const int4 s4 = src4[idx];
                const int4 d4 = dst4[idx];
                int pos;
                pos = atomicAdd(&cur[s4.x >> 8], 1); EP[pos] = ((s4.x & 255) << 16) | d4.x;
                pos = atomicAdd(&cur[s4.y >> 8], 1); EP[pos] = ((s4.y & 255) << 16) | d4.y;
                pos = atomicAdd(&cur[s4.z >> 8], 1); EP[pos] = ((s4.z & 255) << 16) | d4.z;
                pos = atomicAdd(&cur[s4.w >> 8], 1); EP[pos] = ((s4.w & 255) << 16) | d4.w;
            }
        }
        return;
    }

    // ---------------- gemm1v: V1 = relu(F@W1+b1) @ Mb ----------------
    const int gb = blockIdx.x - NHB;
    const int lane = t & 63;
    const int w = t >> 6;

    for (int i = t; i < (128 * PAD) / 8; i += 256)
        reinterpret_cast<uint4*>(Wt)[i] = reinterpret_cast<const uint4*>(Wt_g)[i];
    if (t < 128) bl[t] = b[t];

    const int base = gb * 64;
    const int nRows = min(64, NN - base);
    {
        const int r = t >> 2;
        const int c0 = (t & 3) * 32;
        if (r < nRows) {
            #pragma unroll
            for (int j = 0; j < 32; j += 4) {
                const float4 v = *reinterpret_cast<const float4*>(&X[(size_t)(base + r) * CH + c0 + j]);
                ushort4 o; o.x = f2bf(v.x); o.y = f2bf(v.y); o.z = f2bf(v.z); o.w = f2bf(v.w);
                *reinterpret_cast<ushort4*>(&Fa[r * PAD + c0 + j]) = o;
            }
        } else {
            #pragma unroll
            for (int j = 0; j < 32; j += 4) {
                ushort4 z; z.x = z.y = z.z = z.w = 0;
                *reinterpret_cast<ushort4*>(&Fa[r * PAD + c0 + j]) = z;
            }
        }
    }
    __syncthreads();

    f32x4 acc[8];
    #pragma unroll
    for (int i = 0; i < 8; ++i) acc[i] = (f32x4){0.f, 0.f, 0.f, 0.f};

    const int arow = w * 16 + (lane & 15);
    const int kgrp = (lane >> 4) * 4;

    #pragma unroll
    for (int ks = 0; ks < 4; ++ks) {
        const int k0 = ks * 32 + kgrp;
        bf16x8 af;
        {
            const short4 lo = *reinterpret_cast<const short4*>(&Fa[arow * PAD + k0]);
            const short4 hi = *reinterpret_cast<const short4*>(&Fa[arow * PAD + k0 + 16]);
            af[0] = lo.x; af[1] = lo.y; af[2] = lo.z; af[3] = lo.w;
            af[4] = hi.x; af[5] = hi.y; af[6] = hi.z; af[7] = hi.w;
        }
        #pragma unroll
        for (int ct = 0; ct < 8; ++ct) {
            const int c = ct * 16 + (lane & 15);
            bf16x8 bf;
            const short4 lo = *reinterpret_cast<const short4*>(&Wt[c * PAD + k0]);
            const short4 hi = *reinterpret_cast<const short4*>(&Wt[c * PAD + k0 + 16]);
            bf[0] = lo.x; bf[1] = lo.y; bf[2] = lo.z; bf[3] = lo.w;
            bf[4] = hi.x; bf[5] = hi.y; bf[6] = hi.z; bf[7] = hi.w;
            acc[ct] = __builtin_amdgcn_mfma_f32_16x16x32_bf16(af, bf, acc[ct], 0, 0, 0);
        }
    }
    __syncthreads();

    #pragma unroll
    for (int ct = 0; ct < 8; ++ct) {
        const int c = ct * 16 + (lane & 15);
        const float bias = bl[c];
        #pragma unroll
        for (int r = 0; r < 4; ++r) {
            const int row = w * 16 + (lane >> 4) * 4 + r;
            Fa[row * PAD + c] = f2bf(fmaxf(acc[ct][r] + bias, 0.f));
        }
    }
    __syncthreads();

    f32x4 acc2[3];
    #pragma unroll
    for (int i = 0; i < 3; ++i) acc2[i] = (f32x4){0.f, 0.f, 0.f, 0.f};

    #pragma unroll
    for (int ks = 0; ks < 4; ++ks) {
        const int k0 = ks * 32 + kgrp;
        bf16x8 af;
        {
            const short4 lo = *reinterpret_cast<const short4*>(&Fa[arow * PAD + k0]);
            const short4 hi = *reinterpret_cast<const short4*>(&Fa[arow * PAD + k0 + 16]);
            af[0] = lo.x; af[1] = lo.y; af[2] = lo.z; af[3] = lo.w;
            af[4] = hi.x; af[5] = hi.y; af[6] = hi.z; af[7] = hi.w;
        }
        #pragma unroll
        for (int ct = 0; ct < 3; ++ct) {
            const int c = ct * 16 + (lane & 15);
            bf16x8 bf;
            const short4 lo = *reinterpret_cast<const short4*>(&Mt[c * 128 + k0]);
            const short4 hi = *reinterpret_cast<const short4*>(&Mt[c * 128 + k0 + 16]);
            bf[0] = lo.x; bf[1] = lo.y; bf[2] = lo.z; bf[3] = lo.w;
            bf[4] = hi.x; bf[5] = hi.y; bf[6] = hi.z; bf[7] = hi.w;
            acc2[ct] = __builtin_amdgcn_mfma_f32_16x16x32_bf16(af, bf, acc2[ct], 0, 0, 0);
        }
    }

    #pragma unroll
    for (int ct = 0; ct < 3; ++ct) {
        const int c = ct * 16 + (lane & 15);
        if (c < NCLS) {
            #pragma unroll
            for (int r = 0; r < 4; ++r) {
                const int row = w * 16 + (lane >> 4) * 4 + r;
                Va[row * NCLS + c] = f2bf(acc2[ct][r]);
            }
        }
    }
    __syncthreads();

    // write all 8 replicas (64 rows x 80 B = 320 uint4 each)
    for (int i = t; i < 320 * NCOPY; i += 256) {
        const int cp = i / 320;
        const int j  = i % 320;
        const int r = j / 5;
        const int q = j % 5;
        *reinterpret_cast<uint4*>(&V1R[(size_t)cp * VSTRIDE + (size_t)(base + r) * NCLS + q * 8]) =
            *reinterpret_cast<const uint4*>(&Va[r * NCLS + q * 8]);
    }
}

// ---------------------------------------------------------------------------
// sortgather: 782 blocks x 512 thr; block b owns nodes [b*64, b*64+64).
// Filters parent coarse segment into LDS, counting-sorts, writes sdst/offs/deg,
// then gathers V1 rows (LOCAL-XCD replica) -> U1 (all 8 replicas).
// ---------------------------------------------------------------------------
__global__ __launch_bounds__(512)
void sortgather(const int* __restrict__ H, const int* __restrict__ bsum,
                const int* __restrict__ EP, const unsigned short* __restrict__ V1R,
                unsigned short* __restrict__ U1R, unsigned short* __restrict__ sdst,
                int* __restrict__ offs, int* __restrict__ deg)
{
    __shared__ int raw[CAP];                  // 12 KB
    __shared__ unsigned short srt[CAP];       // 6 KB
    __shared__ int hist[NPB], cur[NPB], segBeg[NPB + 1];
    __shared__ int cnt;

    const int t = threadIdx.x;
    const int b = blockIdx.x;
    const int cb = b >> 2;                    // coarse bucket
    const int sub = b & 3;                    // 64-node sub-range
    const int node0 = b * NPB;
    const int nNodes = min(NPB, NN - node0);
    const int xb = cb * NHB;
    const int beg = H[xb] + bsum[xb >> SCAN_SHIFT];
    int end;
    if (cb == NBUK_SC - 1) end = NE;
    else { const int xe = (cb + 1) * NHB; end = H[xe] + bsum[xe >> SCAN_SHIFT]; }

    const unsigned short* V1 = V1R + (size_t)xcc_id() * VSTRIDE;  // local replica

    if (t == 0) cnt = 0;
    if (t < NPB) hist[t] = 0;
    __syncthreads();

    // filter parent segment to this sub-range; append into raw (wave-coalesced)
    for (int i = beg + t; i < end; i += 512) {
        const int p = EP[i];
        const int hi = p >> 16;               // 0..255 local node in coarse bucket
        if ((hi >> 6) == sub) {
            const int pos = atomicAdd(&cnt, 1);
            raw[pos] = ((hi & 63) << 16) | (p & 0xFFFF);
        }
    }
    __syncthreads();
    const int C = cnt;                        // <= CAP (22-sigma bound)

    for (int i = t; i < C; i += 512) atomicAdd(&hist[raw[i] >> 16], 1);
    __syncthreads();

    if (t < NPB) cur[t] = hist[t];      // reuse cur as scan buffer
    __syncthreads();
    #pragma unroll
    for (int off = 1; off < NPB; off <<= 1) {
        int x = 0;
        if (t < NPB && t >= off) x = cur[t - off];
        __syncthreads();
        if (t < NPB) cur[t] += x;
        __syncthreads();
    }
    if (t < NPB) segBeg[t] = cur[t] - hist[t];
    if (t == 0) segBeg[NPB] = C;
    __syncthreads();

    if (t < nNodes) {
        offs[node0 + t] = b * CAP + segBeg[t];
        deg[node0 + t] = hist[t];
    }
    if (t < NPB) cur[t] = segBeg[t];
    __syncthreads();

    for (int i = t; i < C; i += 512) {
        const int p = raw[i];
        const int pos = atomicAdd(&cur[p >> 16], 1);
        srt[pos] = (unsigned short)(p & 0xFFFF);
    }
    __syncthreads();

    // write sorted dsts for pass 2 (fixed stride per bucket; contiguous)
    for (int i = t; i < C; i += 512) sdst[b * CAP + i] = srt[i];

    // ---- gather phase: wave w handles nodes w*8..w*8+7; indices from LDS ----
    const int w = t >> 6;
    const int lane = t & 63;
    const int g = lane >> 4;            // edge slot 0..3
    const int L = lane & 15;            // channel-group lane (L<10 active)

    for (int ni = 0; ni < 8; ++ni) {
        const int n = w * 8 + ni;
        if (n >= nNodes) break;
        const int sb = segBeg[n];
        const int se = segBeg[n + 1];
        float a0 = 0.f, a1 = 0.f, a2 = 0.f, a3 = 0.f;

        int i = sb;
        for (; i + 16 <= se; i += 16) {
            const int d0 = srt[i + g];
            const int d1 = srt[i + 4 + g];
            const int d2 = srt[i + 8 + g];
            const int d3 = srt[i + 12 + g];
            if (L < 10) {
                const uint2 v0 = *reinterpret_cast<const uint2*>(&V1[(size_t)d0 * NCLS + L * 4]);
                const uint2 v1 = *reinterpret_cast<const uint2*>(&V1[(size_t)d1 * NCLS + L * 4]);
                const uint2 v2 = *reinterpret_cast<const uint2*>(&V1[(size_t)d2 * NCLS + L * 4]);
                const uint2 v3 = *reinterpret_cast<const uint2*>(&V1[(size_t)d3 * NCLS + L * 4]);
                a0 += bflo(v0.x) + bflo(v1.x) + bflo(v2.x) + bflo(v3.x);
                a1 += bfhi(v0.x) + bfhi(v1.x) + bfhi(v2.x) + bfhi(v3.x);
                a2 += bflo(v0.y) + bflo(v1.y) + bflo(v2.y) + bflo(v3.y);
                a3 += bfhi(v0.y) + bfhi(v1.y) + bfhi(v2.y) + bfhi(v3.y);
            }
        }
        for (; i + 4 <= se; i += 4) {
            const int d = srt[i + g];
            if (L < 10) {
                const uint2 v = *reinterpret_cast<const uint2*>(&V1[(size_t)d * NCLS + L * 4]);
                a0 += bflo(v.x); a1 += bfhi(v.x);
                a2 += bflo(v.y); a3 += bfhi(v.y);
            }
        }
        const int rem = se - i;          // 0..3
        if (g < rem) {
            const int d = srt[i + g];
            if (L < 10) {
                const uint2 v = *reinterpret_cast<const uint2*>(&V1[(size_t)d * NCLS + L * 4]);
                a0 += bflo(v.x); a1 += bfhi(v.x);
                a2 += bflo(v.y); a3 += bfhi(v.y);
            }
        }

        a0 += __shfl_xor(a0, 16); a0 += __shfl_xor(a0, 32);
        a1 += __shfl_xor(a1, 16); a1 += __shfl_xor(a1, 32);
        a2 += __shfl_xor(a2, 16); a2 += __shfl_xor(a2, 32);
        a3 += __shfl_xor(a3, 16); a3 += __shfl_xor(a3, 32);

        if (lane < 16 && L < 10) {
            uint2 o;
            o.x = ((unsigned)f2bf(a1) << 16) | f2bf(a0);
            o.y = ((unsigned)f2bf(a3) << 16) | f2bf(a2);
            #pragma unroll
            for (int cp = 0; cp < NCOPY; ++cp)
                *reinterpret_cast<uint2*>(&U1R[(size_t)cp * VSTRIDE +
                                               (size_t)(node0 + n) * NCLS + L * 4]) = o;
        }
    }
}

// ---------------------------------------------------------------------------
// gather40f (final): out[n] = sum over seg of U1[dst] + deg*cfc + bfc (f32).
// Reads the LOCAL-XCD U1 replica. Segment = [offs[n], offs[n]+deg[n]).
// ---------------------------------------------------------------------------
__global__ __launch_bounds__(512)
void gather40f(const int* __restrict__ offs, const unsigned short* __restrict__ sdst,
               const unsigned short* __restrict__ U1R, float* __restrict__ Yf,
               const int* __restrict__ deg,
               const float* __restrict__ cfc, const float* __restrict__ bfc)
{
    const int t = threadIdx.x;
    const int w = t >> 6;
    const int lane = t & 63;
    const int g = lane >> 4;            // edge slot
    const int L = lane & 15;            // channel-group lane
    const int node0 = blockIdx.x * 32 + w * 4;

    const unsigned short* X = U1R + (size_t)xcc_id() * VSTRIDE;  // local replica

    float4 cf = make_float4(0.f, 0.f, 0.f, 0.f);
    float4 bfv = make_float4(0.f, 0.f, 0.f, 0.f);
    if (L < 10) {
        cf  = *reinterpret_cast<const float4*>(&cfc[L * 4]);
        bfv = *reinterpret_cast<const float4*>(&bfc[L * 4]);
    }

    #pragma unroll
    for (int ni = 0; ni < 4; ++ni) {
        const int n = node0 + ni;
        if (n >= NN) break;
        const int sb = offs[n];
        const int dgi = deg[n];
        const int se = sb + dgi;
        float a0 = 0.f, a1 = 0.f, a2 = 0.f, a3 = 0.f;

        int i = sb;
        for (; i + 16 <= se; i += 16) {
            const int d0 = sdst[i + g];
            const int d1 = sdst[i + 4 + g];
            const int d2 = sdst[i + 8 + g];
            const int d3 = sdst[i + 12 + g];
            if (L < 10) {
                const uint2 v0 = *reinterpret_cast<const uint2*>(&X[(size_t)d0 * NCLS + L * 4]);
                const uint2 v1 = *reinterpret_cast<const uint2*>(&X[(size_t)d1 * NCLS + L * 4]);
                const uint2 v2 = *reinterpret_cast<const uint2*>(&X[(size_t)d2 * NCLS + L * 4]);
                const uint2 v3 = *reinterpret_cast<const uint2*>(&X[(size_t)d3 * NCLS + L * 4]);
                a0 += bflo(v0.x) + bflo(v1.x) + bflo(v2.x) + bflo(v3.x);
                a1 += bfhi(v0.x) + bfhi(v1.x) + bfhi(v2.x) + bfhi(v3.x);
                a2 += bflo(v0.y) + bflo(v1.y) + bflo(v2.y) + bflo(v3.y);
                a3 += bfhi(v0.y) + bfhi(v1.y) + bfhi(v2.y) + bfhi(v3.y);
            }
        }
        for (; i + 4 <= se; i += 4) {
            const int d = sdst[i + g];
            if (L < 10) {
                const uint2 v = *reinterpret_cast<const uint2*>(&X[(size_t)d * NCLS + L * 4]);
                a0 += bflo(v.x); a1 += bfhi(v.x);
                a2 += bflo(v.y); a3 += bfhi(v.y);
            }
        }
        const int rem = se - i;          // 0..3
        if (g < rem) {
            const int d = sdst[i + g];
            if (L < 10) {
                const uint2 v = *reinterpret_cast<const uint2*>(&X[(size_t)d * NCLS + L * 4]);
                a0 += bflo(v.x); a1 += bfhi(v.x);
                a2 += bflo(v.y); a3 += bfhi(v.y);
            }
        }

        a0 += __shfl_xor(a0, 16); a0 += __shfl_xor(a0, 32);
        a1 += __shfl_xor(a1, 16); a1 += __shfl_xor(a1, 32);
        a2 += __shfl_xor(a2, 16); a2 += __shfl_xor(a2, 32);
        a3 += __shfl_xor(a3, 16); a3 += __shfl_xor(a3, 32);

        if (lane < 16 && L < 10) {
            const float dgn = (float)dgi;
            float4 o;
            o.x = a0 + dgn * cf.x + bfv.x;
            o.y = a1 + dgn * cf.y + bfv.y;
            o.z = a2 + dgn * cf.z + bfv.z;
            o.w = a3 + dgn * cf.w + bfv.w;
            *reinterpret_cast<float4*>(&Yf[(size_t)n * NCLS + L * 4]) = o;
        }
    }
}

extern "C" void kernel_launch(void* const* d_in, const int* in_sizes, int n_in,
                              void* d_out, int out_size, void* d_ws, size_t ws_size,
                              hipStream_t stream) {
    const float* F   = (const float*)d_in[0];  // (1,N,128)
    const int*   EI  = (const int*)  d_in[1];  // (1,2,E) int32
    const float* W1  = (const float*)d_in[3];
    const float* b1  = (const float*)d_in[4];
    const float* W2  = (const float*)d_in[5];
    const float* b2  = (const float*)d_in[6];
    const float* Wfc = (const float*)d_in[7];
    const float* bfc = (const float*)d_in[8];
    float* out = (float*)d_out;

    char* ws = (char*)d_ws;
    size_t off = 0;
    auto take = [&](size_t bytes) { char* p = ws + off; off += (bytes + 63) & ~(size_t)63; return p; };

    unsigned short* V1R  = (unsigned short*)take(VSTRIDE * NCOPY * 2);        // 32 MB
    unsigned short* U1R  = (unsigned short*)take(VSTRIDE * NCOPY * 2);        // 32 MB
    unsigned short* sdst = (unsigned short*)take((size_t)NBUK * CAP * 2);     // 4.8 MB
    int*   EP   = (int*)take((size_t)NE * 4);                                 // 6.4 MB
    int*   H    = (int*)take((size_t)NS * 4);                                 // 153 KB
    int*   bsum = (int*)take((size_t)(NSB + 1) * 4);
    int*   deg  = (int*)take((size_t)NN * 4);
    int*   offs = (int*)take((size_t)(NN + 1) * 4);
    unsigned short* Mt   = (unsigned short*)take((size_t)48 * 128 * 2);       // 12 KB
    unsigned short* Wt_g = (unsigned short*)take((size_t)128 * PAD * 2);      // 34.8 KB
    float* cfc  = (float*)take((size_t)NCLS * 4);

    const int* src = EI;          // edge_index[0,:]
    const int* dst = EI + NE;     // edge_index[1,:]

    // K1: coarse histogram + weight preps (one launch)
    fused_pre<<<NHB + 64 + 24, 256, 0, stream>>>(src, H, W1, Wt_g, W2, Wfc, b2, Mt, cfc);

    // K2-K3: two-level exclusive scan
    scan_local<<<NSB, SCAN_B, 0, stream>>>(H, bsum);
    scan_bsums<<<1, SCAN_B, 0, stream>>>(bsum);

    // K4: coarse bucket_scatter (196 blocks) + gemm1v (782 blocks, 8 replicas)
    fused_mid<<<NHB + GEMM_BLKS, 256, 0, stream>>>(src, dst, H, bsum, EP,
                                                   F, Wt_g, b1, Mt, V1R);

    // K5: filter + LDS sort + gather pass 1 (782 blocks, local-XCD V1 reads)
    sortgather<<<NBUK, 512, 0, stream>>>(H, bsum, EP, V1R, U1R, sdst, offs, deg);

    // K6: out = gather(U1, local-XCD replica) + deg*cfc + bfc
    gather40f<<<(NN + 31) / 32, 512, 0, stream>>>(offs, sdst, U1R, out, deg, cfc, bfc);
}

// Round 21
// 108.459 us; speedup vs baseline: 1.1590x; 1.1590x over previous
//
#include <hip/hip_runtime.h>

static constexpr int NN = 50000;    // nodes
static constexpr int NE = 1600000;  // edges
static constexpr int CH = 128;
static constexpr int NCLS = 40;

static constexpr int NPB  = 64;                        // nodes per gather bucket
static constexpr int NBUK = (NN + NPB - 1) / NPB;      // 782 gather blocks
static constexpr int NPB_SC = 256;                     // nodes per scatter bucket
static constexpr int NBUK_SC = (NN + NPB_SC - 1) / NPB_SC;  // 196
static constexpr int EPB  = 8192;                      // edges per hist/scatter block
static constexpr int NHB  = (NE + EPB - 1) / EPB;      // 196
static constexpr int NS   = NBUK_SC * NHB;             // 38416 hist entries
static constexpr int SCAN_B = 256;
static constexpr int SCAN_SHIFT = 8;                   // log2(SCAN_B)
static constexpr int NSB  = (NS + SCAN_B - 1) / SCAN_B; // 151 (<=256)
static constexpr int NROWP = ((NN + 63) / 64) * 64;    // 50048 padded rows
static constexpr int PAD = 136;                        // W1^T padded row
static constexpr int GEMM_BLKS = (NN + 63) / 64;       // 782
static constexpr int CAP = 3072;                       // max edges per 64-node bucket

typedef __attribute__((ext_vector_type(8))) short bf16x8;
typedef __attribute__((ext_vector_type(4))) float f32x4;

// ---- bf16 helpers (bit-level, RNE) ----
__device__ __forceinline__ float bflo(unsigned v) {
    return __uint_as_float((v & 0xFFFFu) << 16);
}
__device__ __forceinline__ float bfhi(unsigned v) {
    return __uint_as_float(v & 0xFFFF0000u);
}
__device__ __forceinline__ unsigned short f2bf(float f) {
    unsigned u = __float_as_uint(f);
    u += 0x7FFFu + ((u >> 16) & 1u);   // round to nearest even
    return (unsigned short)(u >> 16);
}

// ---------------------------------------------------------------------------
// fused_pre: blocks [0,NHB): edge histogram (src>>8, 196 coarse buckets) -> H
//            blocks [NHB,NHB+64): W1^T bf16 padded transpose -> Wt_g
//            blocks [NHB+64,NHB+88): Mt=(W2@Wfc)^T bf16 + cfc=b2@Wfc
// ---------------------------------------------------------------------------
__global__ __launch_bounds__(256)
void fused_pre(const int* __restrict__ src, int* __restrict__ H,
               const float* __restrict__ W1, unsigned short* __restrict__ Wt_g,
               const float* __restrict__ W2, const float* __restrict__ Wfc,
               const float* __restrict__ b2, unsigned short* __restrict__ Mt,
               float* __restrict__ cfc)
{
    __shared__ int h[NBUK_SC];
    const int t = threadIdx.x;
    const int b = blockIdx.x;

    if (b < NHB) {
        for (int i = t; i < NBUK_SC; i += 256) h[i] = 0;
        __syncthreads();
        const int base4 = b * (EPB / 4);
        const int4* src4 = reinterpret_cast<const int4*>(src);
        for (int i = t; i < EPB / 4; i += 256) {
            const int idx = base4 + i;
            if (idx < NE / 4) {
                const int4 v = src4[idx];
                atomicAdd(&h[v.x >> 8], 1);
                atomicAdd(&h[v.y >> 8], 1);
                atomicAdd(&h[v.z >> 8], 1);
                atomicAdd(&h[v.w >> 8], 1);
            }
        }
        __syncthreads();
        for (int i = t; i < NBUK_SC; i += 256) H[i * NHB + b] = h[i];
    } else if (b < NHB + 64) {
        const int idx = (b - NHB) * 256 + t;   // 0..16383
        const int c = idx >> 7;
        const int k = idx & 127;
        Wt_g[c * PAD + k] = f2bf(W1[k * 128 + c]);
    } else {
        const int idx = (b - NHB - 64) * 256 + t;   // 0..6143
        if (idx < 48 * 128) {
            const int c = idx >> 7;
            const int k = idx & 127;
            float a = 0.f;
            if (c < NCLS) {
                #pragma unroll 16
                for (int j = 0; j < 128; ++j) a += W2[k * 128 + j] * Wfc[j * NCLS + c];
            }
            Mt[c * 128 + k] = f2bf(a);
        }
        if (b == NHB + 64 && t < NCLS) {
            float a = 0.f;
            #pragma unroll 16
            for (int j = 0; j < 128; ++j) a += b2[j] * Wfc[j * NCLS + t];
            cfc[t] = a;
        }
    }
}

__global__ __launch_bounds__(SCAN_B)
void scan_local(int* __restrict__ H, int* __restrict__ bsum)
{
    __shared__ int buf[SCAN_B];
    const int t = threadIdx.x;
    const int g = blockIdx.x * SCAN_B + t;
    const int v = (g < NS) ? H[g] : 0;
    buf[t] = v;
    __syncthreads();
    #pragma unroll
    for (int off = 1; off < SCAN_B; off <<= 1) {
        const int x = (t >= off) ? buf[t - off] : 0;
        __syncthreads();
        buf[t] += x;
        __syncthreads();
    }
    if (g < NS) H[g] = buf[t] - v;     // exclusive within scan-block
    if (t == SCAN_B - 1) bsum[blockIdx.x] = buf[t];
}

__global__ __launch_bounds__(SCAN_B)
void scan_bsums(int* __restrict__ bsum)
{
    __shared__ int buf[SCAN_B];
    const int t = threadIdx.x;
    const int v = (t < NSB) ? bsum[t] : 0;
    buf[t] = v;
    __syncthreads();
    #pragma unroll
    for (int off = 1; off < SCAN_B; off <<= 1) {
        const int x = (t >= off) ? buf[t - off] : 0;
        __syncthreads();
        buf[t] += x;
        __syncthreads();
    }
    if (t < NSB) bsum[t] = buf[t] - v;  // exclusive base per scan-block
    if (t == SCAN_B - 1) bsum[NSB] = buf[t];
}

// ---------------------------------------------------------------------------
// fused_mid: blocks [0,NHB): coarse bucket_scatter (196 buckets, ~42-edge
// runs -> low write amp, cur[196]); blocks [NHB,+782): gemm1v.
// EP packs ((src&255)<<16) | dst.
// ---------------------------------------------------------------------------
__global__ __launch_bounds__(256)
void fused_mid(const int* __restrict__ src, const int* __restrict__ dst,
               const int* __restrict__ H, const int* __restrict__ bsum,
               int* __restrict__ EP,
               const float* __restrict__ X, const unsigned short* __restrict__ Wt_g,
               const float* __restrict__ b, const unsigned short* __restrict__ Mt,
               unsigned short* __restrict__ V1)
{
    __shared__ __align__(16) unsigned short Wt[128 * PAD];   // 34.8 KB
    __shared__ __align__(16) unsigned short Fa[64 * PAD];    // 17.4 KB
    __shared__ __align__(16) unsigned short Va[64 * NCLS];   // 5 KB
    __shared__ float bl[128];
    __shared__ int cur[NBUK_SC];

    const int t = threadIdx.x;

    if (blockIdx.x < NHB) {
        // ---------------- coarse bucket_scatter ----------------
        const int bb = blockIdx.x;
        for (int i = t; i < NBUK_SC; i += 256) {
            const int x = i * NHB + bb;
            cur[i] = H[x] + bsum[x >> SCAN_SHIFT];
        }
        __syncthreads();
        const int base4 = bb * (EPB / 4);
        const int4* src4 = reinterpret_cast<const int4*>(src);
        const int4* dst4 = reinterpret_cast<const int4*>(dst);
        for (int i = t; i < EPB / 4; i += 256) {
            const int idx = base4 + i;
            if (idx < NE / 4) {
                const int4 s4 = src4[idx];
                const int4 d4 = dst4[idx];
                int pos;
                pos = atomicAdd(&cur[s4.x >> 8], 1); EP[pos] = ((s4.x & 255) << 16) | d4.x;
                pos = atomicAdd(&cur[s4.y >> 8], 1); EP[pos] = ((s4.y & 255) << 16) | d4.y;
                pos = atomicAdd(&cur[s4.z >> 8], 1); EP[pos] = ((s4.z & 255) << 16) | d4.z;
                pos = atomicAdd(&cur[s4.w >> 8], 1); EP[pos] = ((s4.w & 255) << 16) | d4.w;
            }
        }
        return;
    }

    // ---------------- gemm1v: V1 = relu(F@W1+b1) @ Mb ----------------
    const int gb = blockIdx.x - NHB;
    const int lane = t & 63;
    const int w = t >> 6;

    for (int i = t; i < (128 * PAD) / 8; i += 256)
        reinterpret_cast<uint4*>(Wt)[i] = reinterpret_cast<const uint4*>(Wt_g)[i];
    if (t < 128) bl[t] = b[t];

    const int base = gb * 64;
    const int nRows = min(64, NN - base);
    {
        const int r = t >> 2;
        const int c0 = (t & 3) * 32;
        if (r < nRows) {
            #pragma unroll
            for (int j = 0; j < 32; j += 4) {
                const float4 v = *reinterpret_cast<const float4*>(&X[(size_t)(base + r) * CH + c0 + j]);
                ushort4 o; o.x = f2bf(v.x); o.y = f2bf(v.y); o.z = f2bf(v.z); o.w = f2bf(v.w);
                *reinterpret_cast<ushort4*>(&Fa[r * PAD + c0 + j]) = o;
            }
        } else {
            #pragma unroll
            for (int j = 0; j < 32; j += 4) {
                ushort4 z; z.x = z.y = z.z = z.w = 0;
                *reinterpret_cast<ushort4*>(&Fa[r * PAD + c0 + j]) = z;
            }
        }
    }
    __syncthreads();

    f32x4 acc[8];
    #pragma unroll
    for (int i = 0; i < 8; ++i) acc[i] = (f32x4){0.f, 0.f, 0.f, 0.f};

    const int arow = w * 16 + (lane & 15);
    const int kgrp = (lane >> 4) * 4;

    #pragma unroll
    for (int ks = 0; ks < 4; ++ks) {
        const int k0 = ks * 32 + kgrp;
        bf16x8 af;
        {
            const short4 lo = *reinterpret_cast<const short4*>(&Fa[arow * PAD + k0]);
            const short4 hi = *reinterpret_cast<const short4*>(&Fa[arow * PAD + k0 + 16]);
            af[0] = lo.x; af[1] = lo.y; af[2] = lo.z; af[3] = lo.w;
            af[4] = hi.x; af[5] = hi.y; af[6] = hi.z; af[7] = hi.w;
        }
        #pragma unroll
        for (int ct = 0; ct < 8; ++ct) {
            const int c = ct * 16 + (lane & 15);
            bf16x8 bf;
            const short4 lo = *reinterpret_cast<const short4*>(&Wt[c * PAD + k0]);
            const short4 hi = *reinterpret_cast<const short4*>(&Wt[c * PAD + k0 + 16]);
            bf[0] = lo.x; bf[1] = lo.y; bf[2] = lo.z; bf[3] = lo.w;
            bf[4] = hi.x; bf[5] = hi.y; bf[6] = hi.z; bf[7] = hi.w;
            acc[ct] = __builtin_amdgcn_mfma_f32_16x16x32_bf16(af, bf, acc[ct], 0, 0, 0);
        }
    }
    __syncthreads();

    #pragma unroll
    for (int ct = 0; ct < 8; ++ct) {
        const int c = ct * 16 + (lane & 15);
        const float bias = bl[c];
        #pragma unroll
        for (int r = 0; r < 4; ++r) {
            const int row = w * 16 + (lane >> 4) * 4 + r;
            Fa[row * PAD + c] = f2bf(fmaxf(acc[ct][r] + bias, 0.f));
        }
    }
    __syncthreads();

    f32x4 acc2[3];
    #pragma unroll
    for (int i = 0; i < 3; ++i) acc2[i] = (f32x4){0.f, 0.f, 0.f, 0.f};

    #pragma unroll
    for (int ks = 0; ks < 4; ++ks) {
        const int k0 = ks * 32 + kgrp;
        bf16x8 af;
        {
            const short4 lo = *reinterpret_cast<const short4*>(&Fa[arow * PAD + k0]);
            const short4 hi = *reinterpret_cast<const short4*>(&Fa[arow * PAD + k0 + 16]);
            af[0] = lo.x; af[1] = lo.y; af[2] = lo.z; af[3] = lo.w;
            af[4] = hi.x; af[5] = hi.y; af[6] = hi.z; af[7] = hi.w;
        }
        #pragma unroll
        for (int ct = 0; ct < 3; ++ct) {
            const int c = ct * 16 + (lane & 15);
            bf16x8 bf;
            const short4 lo = *reinterpret_cast<const short4*>(&Mt[c * 128 + k0]);
            const short4 hi = *reinterpret_cast<const short4*>(&Mt[c * 128 + k0 + 16]);
            bf[0] = lo.x; bf[1] = lo.y; bf[2] = lo.z; bf[3] = lo.w;
            bf[4] = hi.x; bf[5] = hi.y; bf[6] = hi.z; bf[7] = hi.w;
            acc2[ct] = __builtin_amdgcn_mfma_f32_16x16x32_bf16(af, bf, acc2[ct], 0, 0, 0);
        }
    }

    #pragma unroll
    for (int ct = 0; ct < 3; ++ct) {
        const int c = ct * 16 + (lane & 15);
        if (c < NCLS) {
            #pragma unroll
            for (int r = 0; r < 4; ++r) {
                const int row = w * 16 + (lane >> 4) * 4 + r;
                Va[row * NCLS + c] = f2bf(acc2[ct][r]);
            }
        }
    }
    __syncthreads();

    for (int i = t; i < 320; i += 256) {
        const int r = i / 5;
        const int q = i % 5;
        *reinterpret_cast<uint4*>(&V1[(size_t)(base + r) * NCLS + q * 8]) =
            *reinterpret_cast<const uint4*>(&Va[r * NCLS + q * 8]);
    }
}

// ---------------------------------------------------------------------------
// sortgather: 782 blocks x 512 thr; block b owns nodes [b*64, b*64+64).
// Reads parent coarse segment (cb=b>>2), filters to its 64-node sub-range
// ((hi>>6)==b&3) into LDS, counting-sorts, writes sdst at fixed stride b*CAP
// + offs/deg, then gathers V1 rows via in-LDS sorted indices -> U1.
// ---------------------------------------------------------------------------
__global__ __launch_bounds__(512)
void sortgather(const int* __restrict__ H, const int* __restrict__ bsum,
                const int* __restrict__ EP, const unsigned short* __restrict__ V1,
                unsigned short* __restrict__ U1, unsigned short* __restrict__ sdst,
                int* __restrict__ offs, int* __restrict__ deg)
{
    __shared__ int raw[CAP];                  // 12 KB
    __shared__ unsigned short srt[CAP];       // 6 KB
    __shared__ int hist[NPB], cur[NPB], segBeg[NPB + 1];
    __shared__ int cnt;

    const int t = threadIdx.x;
    const int b = blockIdx.x;
    const int cb = b >> 2;                    // coarse bucket
    const int sub = b & 3;                    // 64-node sub-range
    const int node0 = b * NPB;
    const int nNodes = min(NPB, NN - node0);
    const int xb = cb * NHB;
    const int beg = H[xb] + bsum[xb >> SCAN_SHIFT];
    int end;
    if (cb == NBUK_SC - 1) end = NE;
    else { const int xe = (cb + 1) * NHB; end = H[xe] + bsum[xe >> SCAN_SHIFT]; }

    if (t == 0) cnt = 0;
    if (t < NPB) hist[t] = 0;
    __syncthreads();

    // filter parent segment to this sub-range; append into raw (wave-coalesced)
    for (int i = beg + t; i < end; i += 512) {
        const int p = EP[i];
        const int hi = p >> 16;               // 0..255 local node in coarse bucket
        if ((hi >> 6) == sub) {
            const int pos = atomicAdd(&cnt, 1);
            raw[pos] = ((hi & 63) << 16) | (p & 0xFFFF);
        }
    }
    __syncthreads();
    const int C = cnt;                        // <= CAP (22-sigma bound)

    for (int i = t; i < C; i += 512) atomicAdd(&hist[raw[i] >> 16], 1);
    __syncthreads();

    if (t < NPB) cur[t] = hist[t];      // reuse cur as scan buffer
    __syncthreads();
    #pragma unroll
    for (int off = 1; off < NPB; off <<= 1) {
        int x = 0;
        if (t < NPB && t >= off) x = cur[t - off];
        __syncthreads();
        if (t < NPB) cur[t] += x;
        __syncthreads();
    }
    if (t < NPB) segBeg[t] = cur[t] - hist[t];
    if (t == 0) segBeg[NPB] = C;
    __syncthreads();

    if (t < nNodes) {
        offs[node0 + t] = b * CAP + segBeg[t];
        deg[node0 + t] = hist[t];
    }
    if (t < NPB) cur[t] = segBeg[t];
    __syncthreads();

    for (int i = t; i < C; i += 512) {
        const int p = raw[i];
        const int pos = atomicAdd(&cur[p >> 16], 1);
        srt[pos] = (unsigned short)(p & 0xFFFF);
    }
    __syncthreads();

    // write sorted dsts for pass 2 (fixed stride per bucket; contiguous)
    for (int i = t; i < C; i += 512) sdst[b * CAP + i] = srt[i];

    // ---- gather phase: wave w handles nodes w*8..w*8+7; indices from LDS ----
    const int w = t >> 6;
    const int lane = t & 63;
    const int g = lane >> 4;            // edge slot 0..3
    const int L = lane & 15;            // channel-group lane (L<10 active)

    for (int ni = 0; ni < 8; ++ni) {
        const int n = w * 8 + ni;
        if (n >= nNodes) break;
        const int sb = segBeg[n];
        const int se = segBeg[n + 1];
        float a0 = 0.f, a1 = 0.f, a2 = 0.f, a3 = 0.f;

        int i = sb;
        for (; i + 16 <= se; i += 16) {
            const int d0 = srt[i + g];
            const int d1 = srt[i + 4 + g];
            const int d2 = srt[i + 8 + g];
            const int d3 = srt[i + 12 + g];
            if (L < 10) {
                const uint2 v0 = *reinterpret_cast<const uint2*>(&V1[(size_t)d0 * NCLS + L * 4]);
                const uint2 v1 = *reinterpret_cast<const uint2*>(&V1[(size_t)d1 * NCLS + L * 4]);
                const uint2 v2 = *reinterpret_cast<const uint2*>(&V1[(size_t)d2 * NCLS + L * 4]);
                const uint2 v3 = *reinterpret_cast<const uint2*>(&V1[(size_t)d3 * NCLS + L * 4]);
                a0 += bflo(v0.x) + bflo(v1.x) + bflo(v2.x) + bflo(v3.x);
                a1 += bfhi(v0.x) + bfhi(v1.x) + bfhi(v2.x) + bfhi(v3.x);
                a2 += bflo(v0.y) + bflo(v1.y) + bflo(v2.y) + bflo(v3.y);
                a3 += bfhi(v0.y) + bfhi(v1.y) + bfhi(v2.y) + bfhi(v3.y);
            }
        }
        for (; i + 4 <= se; i += 4) {
            const int d = srt[i + g];
            if (L < 10) {
                const uint2 v = *reinterpret_cast<const uint2*>(&V1[(size_t)d * NCLS + L * 4]);
                a0 += bflo(v.x); a1 += bfhi(v.x);
                a2 += bflo(v.y); a3 += bfhi(v.y);
            }
        }
        const int rem = se - i;          // 0..3
        if (g < rem) {
            const int d = srt[i + g];
            if (L < 10) {
                const uint2 v = *reinterpret_cast<const uint2*>(&V1[(size_t)d * NCLS + L * 4]);
                a0 += bflo(v.x); a1 += bfhi(v.x);
                a2 += bflo(v.y); a3 += bfhi(v.y);
            }
        }

        a0 += __shfl_xor(a0, 16); a0 += __shfl_xor(a0, 32);
        a1 += __shfl_xor(a1, 16); a1 += __shfl_xor(a1, 32);
        a2 += __shfl_xor(a2, 16); a2 += __shfl_xor(a2, 32);
        a3 += __shfl_xor(a3, 16); a3 += __shfl_xor(a3, 32);

        if (lane < 16 && L < 10) {
            uint2 o;
            o.x = ((unsigned)f2bf(a1) << 16) | f2bf(a0);
            o.y = ((unsigned)f2bf(a3) << 16) | f2bf(a2);
            *reinterpret_cast<uint2*>(&U1[(size_t)(node0 + n) * NCLS + L * 4]) = o;
        }
    }
}

// ---------------------------------------------------------------------------
// gather40f (final): out[n] = sum over seg of U1[dst] + deg*cfc + bfc (f32).
// Segment = [offs[n], offs[n]+deg[n]) in fixed-stride sdst.
// ---------------------------------------------------------------------------
__global__ __launch_bounds__(512)
void gather40f(const int* __restrict__ offs, const unsigned short* __restrict__ sdst,
               const unsigned short* __restrict__ X, float* __restrict__ Yf,
               const int* __restrict__ deg,
               const float* __restrict__ cfc, const float* __restrict__ bfc)
{
    const int t = threadIdx.x;
    const int w = t >> 6;
    const int lane = t & 63;
    const int g = lane >> 4;            // edge slot
    const int L = lane & 15;            // channel-group lane
    const int node0 = blockIdx.x * 32 + w * 4;

    float4 cf = make_float4(0.f, 0.f, 0.f, 0.f);
    float4 bfv = make_float4(0.f, 0.f, 0.f, 0.f);
    if (L < 10) {
        cf  = *reinterpret_cast<const float4*>(&cfc[L * 4]);
        bfv = *reinterpret_cast<const float4*>(&bfc[L * 4]);
    }

    #pragma unroll
    for (int ni = 0; ni < 4; ++ni) {
        const int n = node0 + ni;
        if (n >= NN) break;
        const int sb = offs[n];
        const int dgi = deg[n];
        const int se = sb + dgi;
        float a0 = 0.f, a1 = 0.f, a2 = 0.f, a3 = 0.f;

        int i = sb;
        for (; i + 16 <= se; i += 16) {
            const int d0 = sdst[i + g];
            const int d1 = sdst[i + 4 + g];
            const int d2 = sdst[i + 8 + g];
            const int d3 = sdst[i + 12 + g];
            if (L < 10) {
                const uint2 v0 = *reinterpret_cast<const uint2*>(&X[(size_t)d0 * NCLS + L * 4]);
                const uint2 v1 = *reinterpret_cast<const uint2*>(&X[(size_t)d1 * NCLS + L * 4]);
                const uint2 v2 = *reinterpret_cast<const uint2*>(&X[(size_t)d2 * NCLS + L * 4]);
                const uint2 v3 = *reinterpret_cast<const uint2*>(&X[(size_t)d3 * NCLS + L * 4]);
                a0 += bflo(v0.x) + bflo(v1.x) + bflo(v2.x) + bflo(v3.x);
                a1 += bfhi(v0.x) + bfhi(v1.x) + bfhi(v2.x) + bfhi(v3.x);
                a2 += bflo(v0.y) + bflo(v1.y) + bflo(v2.y) + bflo(v3.y);
                a3 += bfhi(v0.y) + bfhi(v1.y) + bfhi(v2.y) + bfhi(v3.y);
            }
        }
        for (; i + 4 <= se; i += 4) {
            const int d = sdst[i + g];
            if (L < 10) {
                const uint2 v = *reinterpret_cast<const uint2*>(&X[(size_t)d * NCLS + L * 4]);
                a0 += bflo(v.x); a1 += bfhi(v.x);
                a2 += bflo(v.y); a3 += bfhi(v.y);
            }
        }
        const int rem = se - i;          // 0..3
        if (g < rem) {
            const int d = sdst[i + g];
            if (L < 10) {
                const uint2 v = *reinterpret_cast<const uint2*>(&X[(size_t)d * NCLS + L * 4]);
                a0 += bflo(v.x); a1 += bfhi(v.x);
                a2 += bflo(v.y); a3 += bfhi(v.y);
            }
        }

        a0 += __shfl_xor(a0, 16); a0 += __shfl_xor(a0, 32);
        a1 += __shfl_xor(a1, 16); a1 += __shfl_xor(a1, 32);
        a2 += __shfl_xor(a2, 16); a2 += __shfl_xor(a2, 32);
        a3 += __shfl_xor(a3, 16); a3 += __shfl_xor(a3, 32);

        if (lane < 16 && L < 10) {
            const float dgn = (float)dgi;
            float4 o;
            o.x = a0 + dgn * cf.x + bfv.x;
            o.y = a1 + dgn * cf.y + bfv.y;
            o.z = a2 + dgn * cf.z + bfv.z;
            o.w = a3 + dgn * cf.w + bfv.w;
            *reinterpret_cast<float4*>(&Yf[(size_t)n * NCLS + L * 4]) = o;
        }
    }
}

extern "C" void kernel_launch(void* const* d_in, const int* in_sizes, int n_in,
                              void* d_out, int out_size, void* d_ws, size_t ws_size,
                              hipStream_t stream) {
    const float* F   = (const float*)d_in[0];  // (1,N,128)
    const int*   EI  = (const int*)  d_in[1];  // (1,2,E) int32
    const float* W1  = (const float*)d_in[3];
    const float* b1  = (const float*)d_in[4];
    const float* W2  = (const float*)d_in[5];
    const float* b2  = (const float*)d_in[6];
    const float* Wfc = (const float*)d_in[7];
    const float* bfc = (const float*)d_in[8];
    float* out = (float*)d_out;

    char* ws = (char*)d_ws;
    size_t off = 0;
    auto take = [&](size_t bytes) { char* p = ws + off; off += (bytes + 63) & ~(size_t)63; return p; };

    unsigned short* V1   = (unsigned short*)take((size_t)NROWP * NCLS * 2);   // 4.0 MB
    unsigned short* U1   = (unsigned short*)take((size_t)NROWP * NCLS * 2);   // 4.0 MB
    unsigned short* sdst = (unsigned short*)take((size_t)NBUK * CAP * 2);     // 4.8 MB
    int*   EP   = (int*)take((size_t)NE * 4);                                 // 6.4 MB
    int*   H    = (int*)take((size_t)NS * 4);                                 // 153 KB
    int*   bsum = (int*)take((size_t)(NSB + 1) * 4);
    int*   deg  = (int*)take((size_t)NN * 4);
    int*   offs = (int*)take((size_t)(NN + 1) * 4);
    unsigned short* Mt   = (unsigned short*)take((size_t)48 * 128 * 2);       // 12 KB
    unsigned short* Wt_g = (unsigned short*)take((size_t)128 * PAD * 2);      // 34.8 KB
    float* cfc  = (float*)take((size_t)NCLS * 4);

    const int* src = EI;          // edge_index[0,:]
    const int* dst = EI + NE;     // edge_index[1,:]

    // K1: coarse histogram + weight preps (one launch)
    fused_pre<<<NHB + 64 + 24, 256, 0, stream>>>(src, H, W1, Wt_g, W2, Wfc, b2, Mt, cfc);

    // K2-K3: two-level exclusive scan
    scan_local<<<NSB, SCAN_B, 0, stream>>>(H, bsum);
    scan_bsums<<<1, SCAN_B, 0, stream>>>(bsum);

    // K4: coarse bucket_scatter (196 blocks) + gemm1v (782 blocks) overlapped
    fused_mid<<<NHB + GEMM_BLKS, 256, 0, stream>>>(src, dst, H, bsum, EP,
                                                   F, Wt_g, b1, Mt, V1);

    // K5: filter + LDS sort + gather pass 1 (782 blocks)
    sortgather<<<NBUK, 512, 0, stream>>>(H, bsum, EP, V1, U1, sdst, offs, deg);

    // K6: out = gather(U1) + deg*cfc + bfc
    gather40f<<<(NN + 31) / 32, 512, 0, stream>>>(offs, sdst, U1, out, deg, cfc, bfc);
}